// Round 6
// baseline (811.508 us; speedup 1.0000x reference)
//
#include <hip/hip_runtime.h>
#include <cstdint>
#include <cstddef>

// ---------------- types ----------------
typedef __bf16 bf16;
typedef __bf16 bf16x4 __attribute__((ext_vector_type(4)));
typedef __bf16 bf16x8 __attribute__((ext_vector_type(8)));
typedef _Float16 f16;
typedef _Float16 f16x4 __attribute__((ext_vector_type(4)));
typedef _Float16 f16x8 __attribute__((ext_vector_type(8)));
typedef float  f32x4  __attribute__((ext_vector_type(4)));
typedef unsigned char u8;

#define B_   16
#define N_   1024
#define C_   768
#define H_   12
#define HD_  64
#define M_   (B_*N_)      // 16384 rows
#define MLP_ 3072
#define QKVN 2304         // 3*C
#define WSCALE 64.0f      // weights cast to fp8 at x64 (0.02-scale weights are subnormal in e4m3)
#define WINV  (1.0f/64.0f)

// native v_exp_f32 (exp2); libm exp2f lowers to slow OCML path
__device__ __forceinline__ float fast_exp2(float x) {
  return __builtin_amdgcn_exp2f(x);
}

// fp8 e4m3 (OCP on gfx950) converts via HW packed cvt
__device__ __forceinline__ u8 to_fp8(float a) {
  return (u8)(__builtin_amdgcn_cvt_pk_fp8_f32(a, a, 0, false) & 0xff);
}
__device__ __forceinline__ int to_fp8x4(float v0, float v1, float v2, float v3) {
  int p = __builtin_amdgcn_cvt_pk_fp8_f32(v0, v1, 0, false);
  p = __builtin_amdgcn_cvt_pk_fp8_f32(v2, v3, p, true);
  return p;  // bytes [v0,v1,v2,v3]
}

// tanh-form GELU via native exp2
__device__ __forceinline__ float fast_gelu(float t) {
  float z = 2.30220568f * (t + 0.044715f * t * t * t);
  return t / (1.0f + fast_exp2(-z));
}

// ---------------- weight cast + transpose: w[K][N] f32 -> wt[N][K] fp8 (x64) ----------------
__global__ void transpose_cast(const float* __restrict__ w, u8* __restrict__ wt,
                               int K, int N) {
  __shared__ float tile[32][33];
  int n0 = blockIdx.x * 32, k0 = blockIdx.y * 32;
  int tx = threadIdx.x, ty = threadIdx.y;   // block (32,8)
  #pragma unroll
  for (int i = 0; i < 32; i += 8)
    tile[ty + i][tx] = w[(size_t)(k0 + ty + i) * N + n0 + tx];
  __syncthreads();
  #pragma unroll
  for (int i = 0; i < 32; i += 8)
    wt[(size_t)(n0 + ty + i) * K + k0 + tx] = to_fp8(tile[tx][ty + i] * WSCALE);
}

// ---------------- LayerNorm (768) + cast to fp8 ----------------
__global__ __launch_bounds__(256)
void ln_cast_kernel(const float* __restrict__ x, const float* __restrict__ g,
                    const float* __restrict__ bta, u8* __restrict__ y) {
  int row = blockIdx.x;
  int tid = threadIdx.x;
  const float* xr = x + (size_t)row * C_;
  float v0 = xr[tid], v1 = xr[tid + 256], v2 = xr[tid + 512];
  float s  = v0 + v1 + v2;
  float sq = v0 * v0 + v1 * v1 + v2 * v2;
  #pragma unroll
  for (int off = 32; off > 0; off >>= 1) {
    s  += __shfl_xor(s,  off);
    sq += __shfl_xor(sq, off);
  }
  __shared__ float red[8];
  int wave = tid >> 6, lane = tid & 63;
  if (lane == 0) { red[wave] = s; red[4 + wave] = sq; }
  __syncthreads();
  s  = red[0] + red[1] + red[2] + red[3];
  sq = red[4] + red[5] + red[6] + red[7];
  float mean = s * (1.0f / C_);
  float var  = sq * (1.0f / C_) - mean * mean;
  float rstd = rsqrtf(var + 1e-5f);
  u8* yr = y + (size_t)row * C_;
  yr[tid]       = to_fp8((v0 - mean) * rstd * g[tid]       + bta[tid]);
  yr[tid + 256] = to_fp8((v1 - mean) * rstd * g[tid + 256] + bta[tid + 256]);
  yr[tid + 512] = to_fp8((v2 - mean) * rstd * g[tid + 512] + bta[tid + 512]);
}

// ---------------- fp8 GEMM: C[M,N] = A[M,K] @ Bt[N,K]^T, fp32 acc, result x(1/64) ----------
// XCD-aware remap (R4). Register double-staging (R5): tile k+1 is global->VGPR prefetched
// during tile k's MFMA phase; LDS filled by ds_write_b128, so the barrier waits lgkmcnt
// (cheap) instead of draining in-flight global loads (the m97 structural stall).
template <int EPI>
__global__ __launch_bounds__(256, 4)
void gemm_bt(const u8* __restrict__ A, const u8* __restrict__ Bt,
             void* __restrict__ outp, const float* __restrict__ bias,
             const float* __restrict__ ls, const float* __restrict__ resid,
             int M, int N, int K, int nb) {
  constexpr int BM = 128, BN = 128, BK = 64;
  __shared__ __align__(16) u8 As[BM * BK];  // 8 KB
  __shared__ __align__(16) u8 Bs[BN * BK];  // 8 KB
  int tid  = threadIdx.x;
  int lane = tid & 63, wave = tid >> 6;
  int quad = lane >> 4, l16 = lane & 15;
  int bid = blockIdx.x;
  int xcd = bid & 7, seq = bid >> 3;
  int mi = xcd + 8 * (seq / nb), ni = seq % nb;
  int m0 = mi * BM, n0 = ni * BN;
  int wm = (wave >> 1) * 64, wn = (wave & 1) * 64;

  // staging: thread covers 16B granule g of row r (natural on global side);
  // LDS side granule-swizzled: physical granule = g ^ ((r>>1)&3)
  const u8* ag[2]; const u8* bg[2]; u8* asw[2]; u8* bsw[2];
  #pragma unroll
  for (int s = 0; s < 2; s++) {
    int u = tid + s * 256;
    int r = u >> 2, g = u & 3, gs = g ^ ((r >> 1) & 3);
    ag[s]  = A  + (size_t)(m0 + r) * K + g * 16;
    bg[s]  = Bt + (size_t)(n0 + r) * K + g * 16;
    asw[s] = As + r * 64 + gs * 16;
    bsw[s] = Bs + r * 64 + gs * 16;
  }
  int swz = (l16 >> 1) & 3;

  const f32x4 fz = {0.f, 0.f, 0.f, 0.f};
  f32x4 acc[4][4];
  #pragma unroll
  for (int i = 0; i < 4; i++)
    #pragma unroll
    for (int j = 0; j < 4; j++) acc[i][j] = fz;

  // prefetch tile 0 into registers
  int4 apre[2], bpre[2];
  #pragma unroll
  for (int s = 0; s < 2; s++) {
    apre[s] = *(const int4*)ag[s];
    bpre[s] = *(const int4*)bg[s];
  }

  for (int k0 = 0; k0 < K; k0 += BK) {
    __syncthreads();   // prior iter's ds_reads complete
    #pragma unroll
    for (int s = 0; s < 2; s++) {
      *(int4*)asw[s] = apre[s];
      *(int4*)bsw[s] = bpre[s];
    }
    __syncthreads();   // lgkm drain only — cheap

    // issue next tile's global loads; complete during MFMA below
    if (k0 + BK < K) {
      #pragma unroll
      for (int s = 0; s < 2; s++) {
        apre[s] = *(const int4*)(ag[s] + k0 + BK);
        bpre[s] = *(const int4*)(bg[s] + k0 + BK);
      }
    }

    #pragma unroll
    for (int kk = 0; kk < 2; kk++) {
      int go = (((kk << 1) | (quad >> 1)) ^ swz) * 16 + (quad & 1) * 8;
      long af[4], bfr[4];
      #pragma unroll
      for (int i = 0; i < 4; i++)
        af[i] = *(const long*)(As + (wm + i * 16 + l16) * 64 + go);
      #pragma unroll
      for (int j = 0; j < 4; j++)
        bfr[j] = *(const long*)(Bs + (wn + j * 16 + l16) * 64 + go);
      #pragma unroll
      for (int i = 0; i < 4; i++)
        #pragma unroll
        for (int j = 0; j < 4; j++)
          acc[i][j] = __builtin_amdgcn_mfma_f32_16x16x32_fp8_fp8(af[i], bfr[j],
                                                                 acc[i][j], 0, 0, 0);
    }
  }

  #pragma unroll
  for (int i = 0; i < 4; i++) {
    int rowb = m0 + wm + i * 16 + quad * 4;
    #pragma unroll
    for (int j = 0; j < 4; j++) {
      int col = n0 + wn + j * 16 + l16;
      #pragma unroll
      for (int r = 0; r < 4; r++) {
        float v = acc[i][j][r] * WINV;
        size_t idx = (size_t)(rowb + r) * N + col;
        if constexpr (EPI == 0) {
          ((bf16*)outp)[idx] = (bf16)v;
        } else if constexpr (EPI == 1) {
          ((float*)outp)[idx] = resid[idx] + (v + bias[col]) * ls[col];
        } else if constexpr (EPI == 2) {
          ((u8*)outp)[idx] = to_fp8(fast_gelu(v + bias[col]));
        } else {
          ((float*)outp)[idx] = resid[idx] + (v + bias[col]) * ls[col];
        }
      }
    }
  }
}

// ---------------- V transpose: qkv[.,1536+h*64+d] bf16 -> vt[bh][d][n] f16 ----------------
__global__ void transpose_v(const bf16* __restrict__ qkv, f16* __restrict__ vt) {
  __shared__ bf16 tile[32][33];
  int bh = blockIdx.z;
  int b = bh / H_, h = bh % H_;
  int n0 = blockIdx.x * 32, d0 = blockIdx.y * 32;
  int tx = threadIdx.x, ty = threadIdx.y;   // block (32,8)
  const bf16* src = qkv + (size_t)(b * N_) * QKVN + 2 * C_ + h * HD_;
  #pragma unroll
  for (int i = 0; i < 32; i += 8)
    tile[ty + i][tx] = src[(size_t)(n0 + ty + i) * QKVN + d0 + tx];
  __syncthreads();
  f16* dst = vt + (size_t)bh * HD_ * N_;
  #pragma unroll
  for (int i = 0; i < 32; i += 8)
    dst[(size_t)(d0 + ty + i) * N_ + n0 + tx] = (f16)(float)tile[tx][ty + i];
}

// ---------------- flash attention, S^T formulation ----------------
// 1-D grid 1536, XCD remap: bh = (bid&7) + 8*(seq>>3), q-tile = seq&7
// Register prefetch: next K/V tile loaded into VGPRs during compute.
__global__ __launch_bounds__(256)
void attn_kernel(const bf16* __restrict__ qkv, const f16* __restrict__ vt,
                 u8* __restrict__ o) {
  constexpr int KSTR = 72;    // K tile stride (64 + 8 pad), bf16
  constexpr int VSTR = 136;   // V^T tile stride (128 + 8 pad), f16
  __shared__ __align__(16) bf16 Ks[128 * KSTR];   // 18432 B
  __shared__ __align__(16) f16  Vs[HD_ * VSTR];   // 17408 B

  int tid = threadIdx.x, lane = tid & 63, wave = tid >> 6;
  int quad = lane >> 4, l16 = lane & 15;
  int bid = blockIdx.x;
  int xcd = bid & 7, seq = bid >> 3;
  int bh = xcd + 8 * (seq >> 3);
  int b = bh / H_, h = bh % H_;
  int q0 = (seq & 7) * 128;
  const float CEXP = 0.125f * 1.44269504f;   // scale * log2(e)

  bf16x8 qf[2][2];
  #pragma unroll
  for (int i = 0; i < 2; i++)
    #pragma unroll
    for (int kk = 0; kk < 2; kk++)
      qf[i][kk] = *(const bf16x8*)(qkv + (size_t)(b * N_ + q0 + wave * 32 + i * 16 + l16) * QKVN
                                   + h * HD_ + kk * 32 + quad * 8);

  const f32x4 fz = {0.f, 0.f, 0.f, 0.f};
  f32x4 oacc[2][4];            // O^T[d = quad*4+r][q = l16]
  float m_run[2], l_run[2];
  #pragma unroll
  for (int i = 0; i < 2; i++) {
    #pragma unroll
    for (int jd = 0; jd < 4; jd++) oacc[i][jd] = fz;
    m_run[i] = -1e30f; l_run[i] = 0.f;
  }

  const bf16* kbase = qkv + (size_t)(b * N_) * QKVN + C_ + h * HD_;
  const f16*  vbase = vt + (size_t)bh * HD_ * N_;

  // per-thread staging coords
  int kr[4], kc[4], vr[4], vc[4];
  #pragma unroll
  for (int u = 0; u < 4; u++) {
    int L = tid + u * 256;
    kr[u] = L >> 3;  kc[u] = (L & 7) * 8;
    vr[u] = L >> 4;  vc[u] = (L & 15) * 8;
  }

  // prefetch tile 0 into registers
  bf16x8 kreg[4]; f16x8 vreg[4];
  #pragma unroll
  for (int u = 0; u < 4; u++) {
    kreg[u] = *(const bf16x8*)(kbase + (size_t)kr[u] * QKVN + kc[u]);
    vreg[u] = *(const f16x8*)(vbase + (size_t)vr[u] * N_ + vc[u]);
  }

  for (int kv = 0; kv < N_; kv += 128) {
    __syncthreads();   // prior compute done reading LDS
    #pragma unroll
    for (int u = 0; u < 4; u++) {
      *(bf16x8*)(Ks + kr[u] * KSTR + kc[u]) = kreg[u];
      *(f16x8*)(Vs + vr[u] * VSTR + vc[u])  = vreg[u];
    }
    __syncthreads();

    // issue next tile's loads; they complete during compute below
    if (kv + 128 < N_) {
      #pragma unroll
      for (int u = 0; u < 4; u++) {
        kreg[u] = *(const bf16x8*)(kbase + (size_t)(kv + 128 + kr[u]) * QKVN + kc[u]);
        vreg[u] = *(const f16x8*)(vbase + (size_t)vr[u] * N_ + kv + 128 + vc[u]);
      }
    }

    // S^T = K @ Q^T
    f32x4 sv[2][8];
    #pragma unroll
    for (int i = 0; i < 2; i++)
      #pragma unroll
      for (int kf = 0; kf < 8; kf++) sv[i][kf] = fz;
    #pragma unroll
    for (int kk = 0; kk < 2; kk++) {
      #pragma unroll
      for (int kf = 0; kf < 8; kf++) {
        bf16x8 kb = *(const bf16x8*)(Ks + (kf * 16 + l16) * KSTR + kk * 32 + quad * 8);
        sv[0][kf] = __builtin_amdgcn_mfma_f32_16x16x32_bf16(kb, qf[0][kk], sv[0][kf], 0, 0, 0);
        sv[1][kf] = __builtin_amdgcn_mfma_f32_16x16x32_bf16(kb, qf[1][kk], sv[1][kf], 0, 0, 0);
      }
    }

    // online softmax: keys in regs, queries on l16
    f16x4 pb[2][8];
    #pragma unroll
    for (int i = 0; i < 2; i++) {
      float mx = sv[i][0][0];
      #pragma unroll
      for (int kf = 0; kf < 8; kf++)
        #pragma unroll
        for (int r = 0; r < 4; r++) mx = fmaxf(mx, sv[i][kf][r]);
      mx = fmaxf(mx, __shfl_xor(mx, 16));
      mx = fmaxf(mx, __shfl_xor(mx, 32));
      float mold = m_run[i];
      float mnew = fmaxf(mold, mx);
      float mb   = mnew * CEXP;
      float al   = fast_exp2(mold * CEXP - mb);
      float rs = 0.f;
      #pragma unroll
      for (int kf = 0; kf < 8; kf++) {
        #pragma unroll
        for (int r = 0; r < 4; r++) {
          float p = fast_exp2(sv[i][kf][r] * CEXP - mb);
          pb[i][kf][r] = (f16)p;
          rs += p;
        }
      }
      rs += __shfl_xor(rs, 16);
      rs += __shfl_xor(rs, 32);
      m_run[i] = mnew;
      l_run[i] = l_run[i] * al + rs;
      #pragma unroll
      for (int jd = 0; jd < 4; jd++) oacc[i][jd] *= al;
    }

    // O^T += V^T @ P^T
    #pragma unroll
    for (int kc2 = 0; kc2 < 8; kc2++) {
      #pragma unroll
      for (int jd = 0; jd < 4; jd++) {
        f16x4 va = *(const f16x4*)(Vs + (jd * 16 + l16) * VSTR + kc2 * 16 + quad * 4);
        oacc[0][jd] = __builtin_amdgcn_mfma_f32_16x16x16f16(va, pb[0][kc2], oacc[0][jd], 0, 0, 0);
        oacc[1][jd] = __builtin_amdgcn_mfma_f32_16x16x16f16(va, pb[1][kc2], oacc[1][jd], 0, 0, 0);
      }
    }
  }

  // finalize: O = O^T / l, 4B packed fp8 stores
  #pragma unroll
  for (int i = 0; i < 2; i++) {
    float inv = 1.0f / l_run[i];
    int n = q0 + wave * 32 + i * 16 + l16;
    #pragma unroll
    for (int jd = 0; jd < 4; jd++) {
      int p = to_fp8x4(oacc[i][jd][0] * inv, oacc[i][jd][1] * inv,
                       oacc[i][jd][2] * inv, oacc[i][jd][3] * inv);
      *(int*)(o + (size_t)(b * N_ + n) * C_ + h * HD_ + jd * 16 + quad * 4) = p;
    }
  }
}

// ---------------- host: workspace layout + launch ----------------
#define WQKVT_OFF  0u
#define WPROJT_OFF 1769472u
#define WFC1T_OFF  2359296u
#define WFC2T_OFF  4718592u
#define Y_OFF      7077888u
#define QKV_OFF    19660800u    // bf16 qkv (75.5 MB); aliased by fp8 hbuf (50.3 MB) after attn
#define VT_OFF     95158272u
#define O_OFF      120324096u
#define X1_OFF     132907008u
#define WS_NEEDED  183238656u

extern "C" void kernel_launch(void* const* d_in, const int* in_sizes, int n_in,
                              void* d_out, int out_size, void* d_ws, size_t ws_size,
                              hipStream_t stream) {
  if (ws_size < (size_t)WS_NEEDED) return;

  const float* x      = (const float*)d_in[0];
  const float* w_qkv  = (const float*)d_in[1];
  const float* w_proj = (const float*)d_in[2];
  const float* b_proj = (const float*)d_in[3];
  const float* ln1_g  = (const float*)d_in[4];
  const float* ln1_b  = (const float*)d_in[5];
  const float* ln2_g  = (const float*)d_in[6];
  const float* ln2_b  = (const float*)d_in[7];
  const float* ls1_g  = (const float*)d_in[8];
  const float* ls2_g  = (const float*)d_in[9];
  const float* w_fc1  = (const float*)d_in[10];
  const float* b_fc1  = (const float*)d_in[11];
  const float* w_fc2  = (const float*)d_in[12];
  const float* b_fc2  = (const float*)d_in[13];

  char* ws = (char*)d_ws;
  u8*    wqkvT  = (u8*)(ws + WQKVT_OFF);
  u8*    wprojT = (u8*)(ws + WPROJT_OFF);
  u8*    wfc1T  = (u8*)(ws + WFC1T_OFF);
  u8*    wfc2T  = (u8*)(ws + WFC2T_OFF);
  u8*    y      = (u8*)(ws + Y_OFF);
  bf16*  qkv    = (bf16*)(ws + QKV_OFF);
  u8*    hbuf   = (u8*)(ws + QKV_OFF);   // alias: qkv dead after attention
  f16*   vt     = (f16*)(ws + VT_OFF);
  u8*    o      = (u8*)(ws + O_OFF);
  float* x1     = (float*)(ws + X1_OFF);
  float* out    = (float*)d_out;

  dim3 tb(32, 8);
  transpose_cast<<<dim3(QKVN / 32, C_ / 32), tb, 0, stream>>>(w_qkv,  wqkvT,  C_,   QKVN);
  transpose_cast<<<dim3(C_   / 32, C_ / 32), tb, 0, stream>>>(w_proj, wprojT, C_,   C_);
  transpose_cast<<<dim3(MLP_ / 32, C_ / 32), tb, 0, stream>>>(w_fc1,  wfc1T,  C_,   MLP_);
  transpose_cast<<<dim3(C_ / 32, MLP_ / 32), tb, 0, stream>>>(w_fc2,  wfc2T,  MLP_, C_);

  ln_cast_kernel<<<M_, 256, 0, stream>>>(x, ln1_g, ln1_b, y);

  gemm_bt<0><<<(QKVN / 128) * 128, 256, 0, stream>>>(
      y, wqkvT, qkv, nullptr, nullptr, nullptr, M_, QKVN, C_, QKVN / 128);

  transpose_v<<<dim3(N_ / 32, HD_ / 32, B_ * H_), tb, 0, stream>>>(qkv, vt);

  attn_kernel<<<(N_ / 128) * B_ * H_, 256, 0, stream>>>(qkv, vt, o);

  gemm_bt<1><<<(C_ / 128) * 128, 256, 0, stream>>>(
      o, wprojT, x1, b_proj, ls1_g, x, M_, C_, C_, C_ / 128);

  ln_cast_kernel<<<M_, 256, 0, stream>>>(x1, ln2_g, ln2_b, y);

  gemm_bt<2><<<(MLP_ / 128) * 128, 256, 0, stream>>>(
      y, wfc1T, hbuf, b_fc1, nullptr, nullptr, M_, MLP_, C_, MLP_ / 128);

  gemm_bt<3><<<(C_ / 128) * 128, 256, 0, stream>>>(
      hbuf, wfc2T, out, b_fc2, ls2_g, x1, M_, C_, MLP_, C_ / 128);
}

// Round 7
// 535.211 us; speedup vs baseline: 1.5162x; 1.5162x over previous
//
#include <hip/hip_runtime.h>
#include <cstdint>
#include <cstddef>

// ---------------- types ----------------
typedef __bf16 bf16;
typedef __bf16 bf16x4 __attribute__((ext_vector_type(4)));
typedef __bf16 bf16x8 __attribute__((ext_vector_type(8)));
typedef _Float16 f16;
typedef _Float16 f16x4 __attribute__((ext_vector_type(4)));
typedef _Float16 f16x8 __attribute__((ext_vector_type(8)));
typedef float  f32x4  __attribute__((ext_vector_type(4)));
typedef unsigned char u8;

#define B_   16
#define N_   1024
#define C_   768
#define H_   12
#define HD_  64
#define M_   (B_*N_)      // 16384 rows
#define MLP_ 3072
#define QKVN 2304         // 3*C
#define WSCALE 64.0f      // weights cast to fp8 at x64 (0.02-scale weights are subnormal in e4m3)
#define WINV  (1.0f/64.0f)

__device__ __forceinline__ void gll16(const void* g, void* l) {
  __builtin_amdgcn_global_load_lds((const __attribute__((address_space(1))) void*)g,
                                   (__attribute__((address_space(3))) void*)l,
                                   16, 0, 0);
}

// native v_exp_f32 (exp2); libm exp2f lowers to slow OCML path
__device__ __forceinline__ float fast_exp2(float x) {
  return __builtin_amdgcn_exp2f(x);
}

// fp8 e4m3 (OCP on gfx950) converts via HW packed cvt
__device__ __forceinline__ u8 to_fp8(float a) {
  return (u8)(__builtin_amdgcn_cvt_pk_fp8_f32(a, a, 0, false) & 0xff);
}
__device__ __forceinline__ int to_fp8x4(float v0, float v1, float v2, float v3) {
  int p = __builtin_amdgcn_cvt_pk_fp8_f32(v0, v1, 0, false);
  p = __builtin_amdgcn_cvt_pk_fp8_f32(v2, v3, p, true);
  return p;  // bytes [v0,v1,v2,v3]
}

// tanh-form GELU via native exp2
__device__ __forceinline__ float fast_gelu(float t) {
  float z = 2.30220568f * (t + 0.044715f * t * t * t);
  return t / (1.0f + fast_exp2(-z));
}

// ---------------- weight cast + transpose: w[K][N] f32 -> wt[N][K] fp8 (x64) ----------------
__global__ void transpose_cast(const float* __restrict__ w, u8* __restrict__ wt,
                               int K, int N) {
  __shared__ float tile[32][33];
  int n0 = blockIdx.x * 32, k0 = blockIdx.y * 32;
  int tx = threadIdx.x, ty = threadIdx.y;   // block (32,8)
  #pragma unroll
  for (int i = 0; i < 32; i += 8)
    tile[ty + i][tx] = w[(size_t)(k0 + ty + i) * N + n0 + tx];
  __syncthreads();
  #pragma unroll
  for (int i = 0; i < 32; i += 8)
    wt[(size_t)(n0 + ty + i) * K + k0 + tx] = to_fp8(tile[tx][ty + i] * WSCALE);
}

// ---------------- LayerNorm (768) + cast to fp8 ----------------
__global__ __launch_bounds__(256)
void ln_cast_kernel(const float* __restrict__ x, const float* __restrict__ g,
                    const float* __restrict__ bta, u8* __restrict__ y) {
  int row = blockIdx.x;
  int tid = threadIdx.x;
  const float* xr = x + (size_t)row * C_;
  float v0 = xr[tid], v1 = xr[tid + 256], v2 = xr[tid + 512];
  float s  = v0 + v1 + v2;
  float sq = v0 * v0 + v1 * v1 + v2 * v2;
  #pragma unroll
  for (int off = 32; off > 0; off >>= 1) {
    s  += __shfl_xor(s,  off);
    sq += __shfl_xor(sq, off);
  }
  __shared__ float red[8];
  int wave = tid >> 6, lane = tid & 63;
  if (lane == 0) { red[wave] = s; red[4 + wave] = sq; }
  __syncthreads();
  s  = red[0] + red[1] + red[2] + red[3];
  sq = red[4] + red[5] + red[6] + red[7];
  float mean = s * (1.0f / C_);
  float var  = sq * (1.0f / C_) - mean * mean;
  float rstd = rsqrtf(var + 1e-5f);
  u8* yr = y + (size_t)row * C_;
  yr[tid]       = to_fp8((v0 - mean) * rstd * g[tid]       + bta[tid]);
  yr[tid + 256] = to_fp8((v1 - mean) * rstd * g[tid + 256] + bta[tid + 256]);
  yr[tid + 512] = to_fp8((v2 - mean) * rstd * g[tid + 512] + bta[tid + 512]);
}

// ---------------- fp8 GEMM: C[M,N] = A[M,K] @ Bt[N,K]^T, fp32 acc, result x(1/64) ----------
// XCD-aware remap (R4). LDS DOUBLE-BUFFER, single barrier per iter (R6):
// barrier's mandatory vmcnt(0) drain now waits on gll16s issued one full compute
// phase earlier (~free); tile k+1's gll16 is issued right after the barrier into
// the buffer the barrier just proved free. No VGPR cost (gll16 bypasses regs) —
// avoids R5's spill disaster (launch_bounds squeezed unified VGPR+AGPR file).
template <int EPI>
__global__ __launch_bounds__(256)
void gemm_bt(const u8* __restrict__ A, const u8* __restrict__ Bt,
             void* __restrict__ outp, const float* __restrict__ bias,
             const float* __restrict__ ls, const float* __restrict__ resid,
             int M, int N, int K, int nb) {
  constexpr int BM = 128, BN = 128, BK = 64;
  __shared__ __align__(16) u8 As[2][BM * BK];  // 2 x 8 KB
  __shared__ __align__(16) u8 Bs[2][BM * BK];  // 2 x 8 KB
  int tid  = threadIdx.x;
  int lane = tid & 63, wave = tid >> 6;
  int quad = lane >> 4, l16 = lane & 15;
  int bid = blockIdx.x;
  int xcd = bid & 7, seq = bid >> 3;
  int mi = xcd + 8 * (seq / nb), ni = seq % nb;
  int m0 = mi * BM, n0 = ni * BN;
  int wm = (wave >> 1) * 64, wn = (wave & 1) * 64;

  // staging source pointers, granule-swizzled at the global side
  // (gll16 dest must stay lane-contiguous: wave-uniform base + lane*16)
  const u8* ag[2]; const u8* bg[2];
  #pragma unroll
  for (int s = 0; s < 2; s++) {
    int u = tid + s * 256;
    int r = u >> 2, g = (u & 3) ^ ((r >> 1) & 3);
    ag[s] = A  + (size_t)(m0 + r) * K + g * 16;
    bg[s] = Bt + (size_t)(n0 + r) * K + g * 16;
  }
  int swz = (l16 >> 1) & 3;

  const f32x4 fz = {0.f, 0.f, 0.f, 0.f};
  f32x4 acc[4][4];
  #pragma unroll
  for (int i = 0; i < 4; i++)
    #pragma unroll
    for (int j = 0; j < 4; j++) acc[i][j] = fz;

  // prologue: stage tile 0 into buffer 0
  gll16(ag[0], &As[0][0] + tid * 16);
  gll16(ag[1], &As[0][0] + 4096 + tid * 16);
  gll16(bg[0], &Bs[0][0] + tid * 16);
  gll16(bg[1], &Bs[0][0] + 4096 + tid * 16);

  int buf = 0;
  for (int k0 = 0; k0 < K; k0 += BK) {
    __syncthreads();   // drains vmcnt: tile k (issued last iter) ready; other buf free
    if (k0 + BK < K) { // prefetch tile k+1 into the other buffer; waited at NEXT barrier
      gll16(ag[0] + k0 + BK, &As[buf ^ 1][0] + tid * 16);
      gll16(ag[1] + k0 + BK, &As[buf ^ 1][0] + 4096 + tid * 16);
      gll16(bg[0] + k0 + BK, &Bs[buf ^ 1][0] + tid * 16);
      gll16(bg[1] + k0 + BK, &Bs[buf ^ 1][0] + 4096 + tid * 16);
    }
    #pragma unroll
    for (int kk = 0; kk < 2; kk++) {
      int go = (((kk << 1) | (quad >> 1)) ^ swz) * 16 + (quad & 1) * 8;
      long af[4], bfr[4];
      #pragma unroll
      for (int i = 0; i < 4; i++)
        af[i] = *(const long*)(&As[buf][0] + (wm + i * 16 + l16) * 64 + go);
      #pragma unroll
      for (int j = 0; j < 4; j++)
        bfr[j] = *(const long*)(&Bs[buf][0] + (wn + j * 16 + l16) * 64 + go);
      #pragma unroll
      for (int i = 0; i < 4; i++)
        #pragma unroll
        for (int j = 0; j < 4; j++)
          acc[i][j] = __builtin_amdgcn_mfma_f32_16x16x32_fp8_fp8(af[i], bfr[j],
                                                                 acc[i][j], 0, 0, 0);
    }
    buf ^= 1;
  }

  #pragma unroll
  for (int i = 0; i < 4; i++) {
    int rowb = m0 + wm + i * 16 + quad * 4;
    #pragma unroll
    for (int j = 0; j < 4; j++) {
      int col = n0 + wn + j * 16 + l16;
      #pragma unroll
      for (int r = 0; r < 4; r++) {
        float v = acc[i][j][r] * WINV;
        size_t idx = (size_t)(rowb + r) * N + col;
        if constexpr (EPI == 0) {
          ((bf16*)outp)[idx] = (bf16)v;
        } else if constexpr (EPI == 1) {
          ((float*)outp)[idx] = resid[idx] + (v + bias[col]) * ls[col];
        } else if constexpr (EPI == 2) {
          ((u8*)outp)[idx] = to_fp8(fast_gelu(v + bias[col]));
        } else {
          ((float*)outp)[idx] = resid[idx] + (v + bias[col]) * ls[col];
        }
      }
    }
  }
}

// ---------------- V transpose: qkv[.,1536+h*64+d] bf16 -> vt[bh][d][n] f16 ----------------
__global__ void transpose_v(const bf16* __restrict__ qkv, f16* __restrict__ vt) {
  __shared__ bf16 tile[32][33];
  int bh = blockIdx.z;
  int b = bh / H_, h = bh % H_;
  int n0 = blockIdx.x * 32, d0 = blockIdx.y * 32;
  int tx = threadIdx.x, ty = threadIdx.y;   // block (32,8)
  const bf16* src = qkv + (size_t)(b * N_) * QKVN + 2 * C_ + h * HD_;
  #pragma unroll
  for (int i = 0; i < 32; i += 8)
    tile[ty + i][tx] = src[(size_t)(n0 + ty + i) * QKVN + d0 + tx];
  __syncthreads();
  f16* dst = vt + (size_t)bh * HD_ * N_;
  #pragma unroll
  for (int i = 0; i < 32; i += 8)
    dst[(size_t)(d0 + ty + i) * N_ + n0 + tx] = (f16)(float)tile[tx][ty + i];
}

// ---------------- flash attention, S^T formulation ----------------
// 1-D grid 1536, XCD remap: bh = (bid&7) + 8*(seq>>3), q-tile = seq&7
// Register prefetch: next K/V tile loaded into VGPRs during compute.
__global__ __launch_bounds__(256)
void attn_kernel(const bf16* __restrict__ qkv, const f16* __restrict__ vt,
                 u8* __restrict__ o) {
  constexpr int KSTR = 72;    // K tile stride (64 + 8 pad), bf16
  constexpr int VSTR = 136;   // V^T tile stride (128 + 8 pad), f16
  __shared__ __align__(16) bf16 Ks[128 * KSTR];   // 18432 B
  __shared__ __align__(16) f16  Vs[HD_ * VSTR];   // 17408 B

  int tid = threadIdx.x, lane = tid & 63, wave = tid >> 6;
  int quad = lane >> 4, l16 = lane & 15;
  int bid = blockIdx.x;
  int xcd = bid & 7, seq = bid >> 3;
  int bh = xcd + 8 * (seq >> 3);
  int b = bh / H_, h = bh % H_;
  int q0 = (seq & 7) * 128;
  const float CEXP = 0.125f * 1.44269504f;   // scale * log2(e)

  bf16x8 qf[2][2];
  #pragma unroll
  for (int i = 0; i < 2; i++)
    #pragma unroll
    for (int kk = 0; kk < 2; kk++)
      qf[i][kk] = *(const bf16x8*)(qkv + (size_t)(b * N_ + q0 + wave * 32 + i * 16 + l16) * QKVN
                                   + h * HD_ + kk * 32 + quad * 8);

  const f32x4 fz = {0.f, 0.f, 0.f, 0.f};
  f32x4 oacc[2][4];            // O^T[d = quad*4+r][q = l16]
  float m_run[2], l_run[2];
  #pragma unroll
  for (int i = 0; i < 2; i++) {
    #pragma unroll
    for (int jd = 0; jd < 4; jd++) oacc[i][jd] = fz;
    m_run[i] = -1e30f; l_run[i] = 0.f;
  }

  const bf16* kbase = qkv + (size_t)(b * N_) * QKVN + C_ + h * HD_;
  const f16*  vbase = vt + (size_t)bh * HD_ * N_;

  // per-thread staging coords
  int kr[4], kc[4], vr[4], vc[4];
  #pragma unroll
  for (int u = 0; u < 4; u++) {
    int L = tid + u * 256;
    kr[u] = L >> 3;  kc[u] = (L & 7) * 8;
    vr[u] = L >> 4;  vc[u] = (L & 15) * 8;
  }

  // prefetch tile 0 into registers
  bf16x8 kreg[4]; f16x8 vreg[4];
  #pragma unroll
  for (int u = 0; u < 4; u++) {
    kreg[u] = *(const bf16x8*)(kbase + (size_t)kr[u] * QKVN + kc[u]);
    vreg[u] = *(const f16x8*)(vbase + (size_t)vr[u] * N_ + vc[u]);
  }

  for (int kv = 0; kv < N_; kv += 128) {
    __syncthreads();   // prior compute done reading LDS
    #pragma unroll
    for (int u = 0; u < 4; u++) {
      *(bf16x8*)(Ks + kr[u] * KSTR + kc[u]) = kreg[u];
      *(f16x8*)(Vs + vr[u] * VSTR + vc[u])  = vreg[u];
    }
    __syncthreads();

    // issue next tile's loads; they complete during compute below
    if (kv + 128 < N_) {
      #pragma unroll
      for (int u = 0; u < 4; u++) {
        kreg[u] = *(const bf16x8*)(kbase + (size_t)(kv + 128 + kr[u]) * QKVN + kc[u]);
        vreg[u] = *(const f16x8*)(vbase + (size_t)vr[u] * N_ + kv + 128 + vc[u]);
      }
    }

    // S^T = K @ Q^T
    f32x4 sv[2][8];
    #pragma unroll
    for (int i = 0; i < 2; i++)
      #pragma unroll
      for (int kf = 0; kf < 8; kf++) sv[i][kf] = fz;
    #pragma unroll
    for (int kk = 0; kk < 2; kk++) {
      #pragma unroll
      for (int kf = 0; kf < 8; kf++) {
        bf16x8 kb = *(const bf16x8*)(Ks + (kf * 16 + l16) * KSTR + kk * 32 + quad * 8);
        sv[0][kf] = __builtin_amdgcn_mfma_f32_16x16x32_bf16(kb, qf[0][kk], sv[0][kf], 0, 0, 0);
        sv[1][kf] = __builtin_amdgcn_mfma_f32_16x16x32_bf16(kb, qf[1][kk], sv[1][kf], 0, 0, 0);
      }
    }

    // online softmax: keys in regs, queries on l16
    f16x4 pb[2][8];
    #pragma unroll
    for (int i = 0; i < 2; i++) {
      float mx = sv[i][0][0];
      #pragma unroll
      for (int kf = 0; kf < 8; kf++)
        #pragma unroll
        for (int r = 0; r < 4; r++) mx = fmaxf(mx, sv[i][kf][r]);
      mx = fmaxf(mx, __shfl_xor(mx, 16));
      mx = fmaxf(mx, __shfl_xor(mx, 32));
      float mold = m_run[i];
      float mnew = fmaxf(mold, mx);
      float mb   = mnew * CEXP;
      float al   = fast_exp2(mold * CEXP - mb);
      float rs = 0.f;
      #pragma unroll
      for (int kf = 0; kf < 8; kf++) {
        #pragma unroll
        for (int r = 0; r < 4; r++) {
          float p = fast_exp2(sv[i][kf][r] * CEXP - mb);
          pb[i][kf][r] = (f16)p;
          rs += p;
        }
      }
      rs += __shfl_xor(rs, 16);
      rs += __shfl_xor(rs, 32);
      m_run[i] = mnew;
      l_run[i] = l_run[i] * al + rs;
      #pragma unroll
      for (int jd = 0; jd < 4; jd++) oacc[i][jd] *= al;
    }

    // O^T += V^T @ P^T
    #pragma unroll
    for (int kc2 = 0; kc2 < 8; kc2++) {
      #pragma unroll
      for (int jd = 0; jd < 4; jd++) {
        f16x4 va = *(const f16x4*)(Vs + (jd * 16 + l16) * VSTR + kc2 * 16 + quad * 4);
        oacc[0][jd] = __builtin_amdgcn_mfma_f32_16x16x16f16(va, pb[0][kc2], oacc[0][jd], 0, 0, 0);
        oacc[1][jd] = __builtin_amdgcn_mfma_f32_16x16x16f16(va, pb[1][kc2], oacc[1][jd], 0, 0, 0);
      }
    }
  }

  // finalize: O = O^T / l, 4B packed fp8 stores
  #pragma unroll
  for (int i = 0; i < 2; i++) {
    float inv = 1.0f / l_run[i];
    int n = q0 + wave * 32 + i * 16 + l16;
    #pragma unroll
    for (int jd = 0; jd < 4; jd++) {
      int p = to_fp8x4(oacc[i][jd][0] * inv, oacc[i][jd][1] * inv,
                       oacc[i][jd][2] * inv, oacc[i][jd][3] * inv);
      *(int*)(o + (size_t)(b * N_ + n) * C_ + h * HD_ + jd * 16 + quad * 4) = p;
    }
  }
}

// ---------------- host: workspace layout + launch ----------------
#define WQKVT_OFF  0u
#define WPROJT_OFF 1769472u
#define WFC1T_OFF  2359296u
#define WFC2T_OFF  4718592u
#define Y_OFF      7077888u
#define QKV_OFF    19660800u    // bf16 qkv (75.5 MB); aliased by fp8 hbuf (50.3 MB) after attn
#define VT_OFF     95158272u
#define O_OFF      120324096u
#define X1_OFF     132907008u
#define WS_NEEDED  183238656u

extern "C" void kernel_launch(void* const* d_in, const int* in_sizes, int n_in,
                              void* d_out, int out_size, void* d_ws, size_t ws_size,
                              hipStream_t stream) {
  if (ws_size < (size_t)WS_NEEDED) return;

  const float* x      = (const float*)d_in[0];
  const float* w_qkv  = (const float*)d_in[1];
  const float* w_proj = (const float*)d_in[2];
  const float* b_proj = (const float*)d_in[3];
  const float* ln1_g  = (const float*)d_in[4];
  const float* ln1_b  = (const float*)d_in[5];
  const float* ln2_g  = (const float*)d_in[6];
  const float* ln2_b  = (const float*)d_in[7];
  const float* ls1_g  = (const float*)d_in[8];
  const float* ls2_g  = (const float*)d_in[9];
  const float* w_fc1  = (const float*)d_in[10];
  const float* b_fc1  = (const float*)d_in[11];
  const float* w_fc2  = (const float*)d_in[12];
  const float* b_fc2  = (const float*)d_in[13];

  char* ws = (char*)d_ws;
  u8*    wqkvT  = (u8*)(ws + WQKVT_OFF);
  u8*    wprojT = (u8*)(ws + WPROJT_OFF);
  u8*    wfc1T  = (u8*)(ws + WFC1T_OFF);
  u8*    wfc2T  = (u8*)(ws + WFC2T_OFF);
  u8*    y      = (u8*)(ws + Y_OFF);
  bf16*  qkv    = (bf16*)(ws + QKV_OFF);
  u8*    hbuf   = (u8*)(ws + QKV_OFF);   // alias: qkv dead after attention
  f16*   vt     = (f16*)(ws + VT_OFF);
  u8*    o      = (u8*)(ws + O_OFF);
  float* x1     = (float*)(ws + X1_OFF);
  float* out    = (float*)d_out;

  dim3 tb(32, 8);
  transpose_cast<<<dim3(QKVN / 32, C_ / 32), tb, 0, stream>>>(w_qkv,  wqkvT,  C_,   QKVN);
  transpose_cast<<<dim3(C_   / 32, C_ / 32), tb, 0, stream>>>(w_proj, wprojT, C_,   C_);
  transpose_cast<<<dim3(MLP_ / 32, C_ / 32), tb, 0, stream>>>(w_fc1,  wfc1T,  C_,   MLP_);
  transpose_cast<<<dim3(C_ / 32, MLP_ / 32), tb, 0, stream>>>(w_fc2,  wfc2T,  MLP_, C_);

  ln_cast_kernel<<<M_, 256, 0, stream>>>(x, ln1_g, ln1_b, y);

  gemm_bt<0><<<(QKVN / 128) * 128, 256, 0, stream>>>(
      y, wqkvT, qkv, nullptr, nullptr, nullptr, M_, QKVN, C_, QKVN / 128);

  transpose_v<<<dim3(N_ / 32, HD_ / 32, B_ * H_), tb, 0, stream>>>(qkv, vt);

  attn_kernel<<<(N_ / 128) * B_ * H_, 256, 0, stream>>>(qkv, vt, o);

  gemm_bt<1><<<(C_ / 128) * 128, 256, 0, stream>>>(
      o, wprojT, x1, b_proj, ls1_g, x, M_, C_, C_, C_ / 128);

  ln_cast_kernel<<<M_, 256, 0, stream>>>(x1, ln2_g, ln2_b, y);

  gemm_bt<2><<<(MLP_ / 128) * 128, 256, 0, stream>>>(
      y, wfc1T, hbuf, b_fc1, nullptr, nullptr, M_, MLP_, C_, MLP_ / 128);

  gemm_bt<3><<<(C_ / 128) * 128, 256, 0, stream>>>(
      hbuf, wfc2T, out, b_fc2, ls2_g, x1, M_, C_, MLP_, C_ / 128);
}

// Round 8
// 500.414 us; speedup vs baseline: 1.6217x; 1.0695x over previous
//
#include <hip/hip_runtime.h>
#include <cstdint>
#include <cstddef>

// ---------------- types ----------------
typedef __bf16 bf16;
typedef __bf16 bf16x4 __attribute__((ext_vector_type(4)));
typedef __bf16 bf16x8 __attribute__((ext_vector_type(8)));
typedef _Float16 f16;
typedef _Float16 f16x4 __attribute__((ext_vector_type(4)));
typedef _Float16 f16x8 __attribute__((ext_vector_type(8)));
typedef float  f32x4  __attribute__((ext_vector_type(4)));
typedef unsigned char u8;

#define B_   16
#define N_   1024
#define C_   768
#define H_   12
#define HD_  64
#define M_   (B_*N_)      // 16384 rows
#define MLP_ 3072
#define QKVN 2304         // 3*C
#define WSCALE 64.0f      // weights cast to fp8 at x64 (0.02-scale weights are subnormal in e4m3)
#define WINV  (1.0f/64.0f)

__device__ __forceinline__ void gll16(const void* g, void* l) {
  __builtin_amdgcn_global_load_lds((const __attribute__((address_space(1))) void*)g,
                                   (__attribute__((address_space(3))) void*)l,
                                   16, 0, 0);
}

// native v_exp_f32 / v_rcp_f32 — libm forms lower to slow OCML sequences
__device__ __forceinline__ float fast_exp2(float x) { return __builtin_amdgcn_exp2f(x); }
__device__ __forceinline__ float fast_rcp(float x)  { return __builtin_amdgcn_rcpf(x); }

// fp8 e4m3 (OCP on gfx950) converts via HW packed cvt
__device__ __forceinline__ u8 to_fp8(float a) {
  return (u8)(__builtin_amdgcn_cvt_pk_fp8_f32(a, a, 0, false) & 0xff);
}
__device__ __forceinline__ int to_fp8x4(float v0, float v1, float v2, float v3) {
  int p = __builtin_amdgcn_cvt_pk_fp8_f32(v0, v1, 0, false);
  p = __builtin_amdgcn_cvt_pk_fp8_f32(v2, v3, p, true);
  return p;  // bytes [v0,v1,v2,v3]
}

// ---------------- weight cast + transpose: w[K][N] f32 -> wt[N][K] fp8 (x64) ----------------
__global__ void transpose_cast(const float* __restrict__ w, u8* __restrict__ wt,
                               int K, int N) {
  __shared__ float tile[32][33];
  int n0 = blockIdx.x * 32, k0 = blockIdx.y * 32;
  int tx = threadIdx.x, ty = threadIdx.y;   // block (32,8)
  #pragma unroll
  for (int i = 0; i < 32; i += 8)
    tile[ty + i][tx] = w[(size_t)(k0 + ty + i) * N + n0 + tx];
  __syncthreads();
  #pragma unroll
  for (int i = 0; i < 32; i += 8)
    wt[(size_t)(n0 + ty + i) * K + k0 + tx] = to_fp8(tile[tx][ty + i] * WSCALE);
}

// ---------------- LayerNorm (768) + cast to fp8 ----------------
__global__ __launch_bounds__(256)
void ln_cast_kernel(const float* __restrict__ x, const float* __restrict__ g,
                    const float* __restrict__ bta, u8* __restrict__ y) {
  int row = blockIdx.x;
  int tid = threadIdx.x;
  const float* xr = x + (size_t)row * C_;
  float v0 = xr[tid], v1 = xr[tid + 256], v2 = xr[tid + 512];
  float s  = v0 + v1 + v2;
  float sq = v0 * v0 + v1 * v1 + v2 * v2;
  #pragma unroll
  for (int off = 32; off > 0; off >>= 1) {
    s  += __shfl_xor(s,  off);
    sq += __shfl_xor(sq, off);
  }
  __shared__ float red[8];
  int wave = tid >> 6, lane = tid & 63;
  if (lane == 0) { red[wave] = s; red[4 + wave] = sq; }
  __syncthreads();
  s  = red[0] + red[1] + red[2] + red[3];
  sq = red[4] + red[5] + red[6] + red[7];
  float mean = s * (1.0f / C_);
  float var  = sq * (1.0f / C_) - mean * mean;
  float rstd = rsqrtf(var + 1e-5f);
  u8* yr = y + (size_t)row * C_;
  yr[tid]       = to_fp8((v0 - mean) * rstd * g[tid]       + bta[tid]);
  yr[tid + 256] = to_fp8((v1 - mean) * rstd * g[tid + 256] + bta[tid + 256]);
  yr[tid + 512] = to_fp8((v2 - mean) * rstd * g[tid + 512] + bta[tid + 512]);
}

// ---------------- fp8 GEMM: C[M,N] = A[M,K] @ Bt[N,K]^T, fp32 acc, result x(1/64) ----------
// XCD-aware remap (R4). LDS double-buffer, single barrier/iter (R6).
// R7: epilogue VALU diet — no division anywhere (v_rcp), sigmoid-GELU with
// constants folded to 2 fma + exp + add + rcp + mul per element.
template <int EPI>
__global__ __launch_bounds__(256)
void gemm_bt(const u8* __restrict__ A, const u8* __restrict__ Bt,
             void* __restrict__ outp, const float* __restrict__ bias,
             const float* __restrict__ ls, const float* __restrict__ resid,
             int M, int N, int K, int nb) {
  constexpr int BM = 128, BN = 128, BK = 64;
  __shared__ __align__(16) u8 As[2][BM * BK];  // 2 x 8 KB
  __shared__ __align__(16) u8 Bs[2][BM * BK];  // 2 x 8 KB
  int tid  = threadIdx.x;
  int lane = tid & 63, wave = tid >> 6;
  int quad = lane >> 4, l16 = lane & 15;
  int bid = blockIdx.x;
  int xcd = bid & 7, seq = bid >> 3;
  int mi = xcd + 8 * (seq / nb), ni = seq % nb;
  int m0 = mi * BM, n0 = ni * BN;
  int wm = (wave >> 1) * 64, wn = (wave & 1) * 64;

  // staging source pointers, granule-swizzled at the global side
  const u8* ag[2]; const u8* bg[2];
  #pragma unroll
  for (int s = 0; s < 2; s++) {
    int u = tid + s * 256;
    int r = u >> 2, g = (u & 3) ^ ((r >> 1) & 3);
    ag[s] = A  + (size_t)(m0 + r) * K + g * 16;
    bg[s] = Bt + (size_t)(n0 + r) * K + g * 16;
  }
  int swz = (l16 >> 1) & 3;

  const f32x4 fz = {0.f, 0.f, 0.f, 0.f};
  f32x4 acc[4][4];
  #pragma unroll
  for (int i = 0; i < 4; i++)
    #pragma unroll
    for (int j = 0; j < 4; j++) acc[i][j] = fz;

  // prologue: stage tile 0 into buffer 0
  gll16(ag[0], &As[0][0] + tid * 16);
  gll16(ag[1], &As[0][0] + 4096 + tid * 16);
  gll16(bg[0], &Bs[0][0] + tid * 16);
  gll16(bg[1], &Bs[0][0] + 4096 + tid * 16);

  int buf = 0;
  for (int k0 = 0; k0 < K; k0 += BK) {
    __syncthreads();   // drains vmcnt: tile k (issued last iter) ready; other buf free
    if (k0 + BK < K) { // prefetch tile k+1 into the other buffer; waited at NEXT barrier
      gll16(ag[0] + k0 + BK, &As[buf ^ 1][0] + tid * 16);
      gll16(ag[1] + k0 + BK, &As[buf ^ 1][0] + 4096 + tid * 16);
      gll16(bg[0] + k0 + BK, &Bs[buf ^ 1][0] + tid * 16);
      gll16(bg[1] + k0 + BK, &Bs[buf ^ 1][0] + 4096 + tid * 16);
    }
    #pragma unroll
    for (int kk = 0; kk < 2; kk++) {
      int go = (((kk << 1) | (quad >> 1)) ^ swz) * 16 + (quad & 1) * 8;
      long af[4], bfr[4];
      #pragma unroll
      for (int i = 0; i < 4; i++)
        af[i] = *(const long*)(&As[buf][0] + (wm + i * 16 + l16) * 64 + go);
      #pragma unroll
      for (int j = 0; j < 4; j++)
        bfr[j] = *(const long*)(&Bs[buf][0] + (wn + j * 16 + l16) * 64 + go);
      #pragma unroll
      for (int i = 0; i < 4; i++)
        #pragma unroll
        for (int j = 0; j < 4; j++)
          acc[i][j] = __builtin_amdgcn_mfma_f32_16x16x32_fp8_fp8(af[i], bfr[j],
                                                                 acc[i][j], 0, 0, 0);
    }
    buf ^= 1;
  }

  // epilogue: D[row][col], row = quad*4 + r, col = l16 (per 16x16 frag)
  #pragma unroll
  for (int i = 0; i < 4; i++) {
    int rowb = m0 + wm + i * 16 + quad * 4;
    #pragma unroll
    for (int j = 0; j < 4; j++) {
      int col = n0 + wn + j * 16 + l16;
      float bias_c = (EPI == 0) ? 0.f : bias[col];
      float ls_c   = (EPI == 1 || EPI == 3) ? ls[col] : 0.f;
      // folded gelu constants (EPI==2): zn = -1.702*log2e*(v*WINV + bias)
      float gz_v = -2.45546696f * WINV;
      float gz_b = -2.45546696f * bias_c;
      #pragma unroll
      for (int r = 0; r < 4; r++) {
        float v = acc[i][j][r];
        size_t idx = (size_t)(rowb + r) * N + col;
        if constexpr (EPI == 0) {
          ((bf16*)outp)[idx] = (bf16)(v * WINV);
        } else if constexpr (EPI == 1) {
          float t = fmaf(v, WINV, bias_c);
          ((float*)outp)[idx] = fmaf(t, ls_c, resid[idx]);
        } else if constexpr (EPI == 2) {
          float t  = fmaf(v, WINV, bias_c);
          float zn = fmaf(v, gz_v, gz_b);
          float gv = t * fast_rcp(1.0f + fast_exp2(zn));   // t * sigmoid(1.702 t)
          ((u8*)outp)[idx] = to_fp8(gv);
        } else {
          float t = fmaf(v, WINV, bias_c);
          ((float*)outp)[idx] = fmaf(t, ls_c, resid[idx]);
        }
      }
    }
  }
}

// ---------------- V transpose: qkv[.,1536+h*64+d] bf16 -> vt[bh][d][n] f16 ----------------
__global__ void transpose_v(const bf16* __restrict__ qkv, f16* __restrict__ vt) {
  __shared__ bf16 tile[32][33];
  int bh = blockIdx.z;
  int b = bh / H_, h = bh % H_;
  int n0 = blockIdx.x * 32, d0 = blockIdx.y * 32;
  int tx = threadIdx.x, ty = threadIdx.y;   // block (32,8)
  const bf16* src = qkv + (size_t)(b * N_) * QKVN + 2 * C_ + h * HD_;
  #pragma unroll
  for (int i = 0; i < 32; i += 8)
    tile[ty + i][tx] = src[(size_t)(n0 + ty + i) * QKVN + d0 + tx];
  __syncthreads();
  f16* dst = vt + (size_t)bh * HD_ * N_;
  #pragma unroll
  for (int i = 0; i < 32; i += 8)
    dst[(size_t)(d0 + ty + i) * N_ + n0 + tx] = (f16)(float)tile[tx][ty + i];
}

// ---------------- flash attention, S^T formulation ----------------
// 1-D grid 1536, XCD remap: bh = (bid&7) + 8*(seq>>3), q-tile = seq&7
// Register prefetch: next K/V tile loaded into VGPRs during compute.
__global__ __launch_bounds__(256)
void attn_kernel(const bf16* __restrict__ qkv, const f16* __restrict__ vt,
                 u8* __restrict__ o) {
  constexpr int KSTR = 72;    // K tile stride (64 + 8 pad), bf16
  constexpr int VSTR = 136;   // V^T tile stride (128 + 8 pad), f16
  __shared__ __align__(16) bf16 Ks[128 * KSTR];   // 18432 B
  __shared__ __align__(16) f16  Vs[HD_ * VSTR];   // 17408 B

  int tid = threadIdx.x, lane = tid & 63, wave = tid >> 6;
  int quad = lane >> 4, l16 = lane & 15;
  int bid = blockIdx.x;
  int xcd = bid & 7, seq = bid >> 3;
  int bh = xcd + 8 * (seq >> 3);
  int b = bh / H_, h = bh % H_;
  int q0 = (seq & 7) * 128;
  const float CEXP = 0.125f * 1.44269504f;   // scale * log2(e)

  bf16x8 qf[2][2];
  #pragma unroll
  for (int i = 0; i < 2; i++)
    #pragma unroll
    for (int kk = 0; kk < 2; kk++)
      qf[i][kk] = *(const bf16x8*)(qkv + (size_t)(b * N_ + q0 + wave * 32 + i * 16 + l16) * QKVN
                                   + h * HD_ + kk * 32 + quad * 8);

  const f32x4 fz = {0.f, 0.f, 0.f, 0.f};
  f32x4 oacc[2][4];            // O^T[d = quad*4+r][q = l16]
  float m_run[2], l_run[2];
  #pragma unroll
  for (int i = 0; i < 2; i++) {
    #pragma unroll
    for (int jd = 0; jd < 4; jd++) oacc[i][jd] = fz;
    m_run[i] = -1e30f; l_run[i] = 0.f;
  }

  const bf16* kbase = qkv + (size_t)(b * N_) * QKVN + C_ + h * HD_;
  const f16*  vbase = vt + (size_t)bh * HD_ * N_;

  // per-thread staging coords
  int kr[4], kc[4], vr[4], vc[4];
  #pragma unroll
  for (int u = 0; u < 4; u++) {
    int L = tid + u * 256;
    kr[u] = L >> 3;  kc[u] = (L & 7) * 8;
    vr[u] = L >> 4;  vc[u] = (L & 15) * 8;
  }

  // prefetch tile 0 into registers
  bf16x8 kreg[4]; f16x8 vreg[4];
  #pragma unroll
  for (int u = 0; u < 4; u++) {
    kreg[u] = *(const bf16x8*)(kbase + (size_t)kr[u] * QKVN + kc[u]);
    vreg[u] = *(const f16x8*)(vbase + (size_t)vr[u] * N_ + vc[u]);
  }

  for (int kv = 0; kv < N_; kv += 128) {
    __syncthreads();   // prior compute done reading LDS
    #pragma unroll
    for (int u = 0; u < 4; u++) {
      *(bf16x8*)(Ks + kr[u] * KSTR + kc[u]) = kreg[u];
      *(f16x8*)(Vs + vr[u] * VSTR + vc[u])  = vreg[u];
    }
    __syncthreads();

    // issue next tile's loads; they complete during compute below
    if (kv + 128 < N_) {
      #pragma unroll
      for (int u = 0; u < 4; u++) {
        kreg[u] = *(const bf16x8*)(kbase + (size_t)(kv + 128 + kr[u]) * QKVN + kc[u]);
        vreg[u] = *(const f16x8*)(vbase + (size_t)vr[u] * N_ + kv + 128 + vc[u]);
      }
    }

    // S^T = K @ Q^T
    f32x4 sv[2][8];
    #pragma unroll
    for (int i = 0; i < 2; i++)
      #pragma unroll
      for (int kf = 0; kf < 8; kf++) sv[i][kf] = fz;
    #pragma unroll
    for (int kk = 0; kk < 2; kk++) {
      #pragma unroll
      for (int kf = 0; kf < 8; kf++) {
        bf16x8 kb = *(const bf16x8*)(Ks + (kf * 16 + l16) * KSTR + kk * 32 + quad * 8);
        sv[0][kf] = __builtin_amdgcn_mfma_f32_16x16x32_bf16(kb, qf[0][kk], sv[0][kf], 0, 0, 0);
        sv[1][kf] = __builtin_amdgcn_mfma_f32_16x16x32_bf16(kb, qf[1][kk], sv[1][kf], 0, 0, 0);
      }
    }

    // online softmax: keys in regs, queries on l16
    f16x4 pb[2][8];
    #pragma unroll
    for (int i = 0; i < 2; i++) {
      float mx = sv[i][0][0];
      #pragma unroll
      for (int kf = 0; kf < 8; kf++)
        #pragma unroll
        for (int r = 0; r < 4; r++) mx = fmaxf(mx, sv[i][kf][r]);
      mx = fmaxf(mx, __shfl_xor(mx, 16));
      mx = fmaxf(mx, __shfl_xor(mx, 32));
      float mold = m_run[i];
      float mnew = fmaxf(mold, mx);
      float mb   = mnew * CEXP;
      float al   = fast_exp2(mold * CEXP - mb);
      float rs = 0.f;
      #pragma unroll
      for (int kf = 0; kf < 8; kf++) {
        #pragma unroll
        for (int r = 0; r < 4; r++) {
          float p = fast_exp2(sv[i][kf][r] * CEXP - mb);
          pb[i][kf][r] = (f16)p;
          rs += p;
        }
      }
      rs += __shfl_xor(rs, 16);
      rs += __shfl_xor(rs, 32);
      m_run[i] = mnew;
      l_run[i] = l_run[i] * al + rs;
      #pragma unroll
      for (int jd = 0; jd < 4; jd++) oacc[i][jd] *= al;
    }

    // O^T += V^T @ P^T
    #pragma unroll
    for (int kc2 = 0; kc2 < 8; kc2++) {
      #pragma unroll
      for (int jd = 0; jd < 4; jd++) {
        f16x4 va = *(const f16x4*)(Vs + (jd * 16 + l16) * VSTR + kc2 * 16 + quad * 4);
        oacc[0][jd] = __builtin_amdgcn_mfma_f32_16x16x16f16(va, pb[0][kc2], oacc[0][jd], 0, 0, 0);
        oacc[1][jd] = __builtin_amdgcn_mfma_f32_16x16x16f16(va, pb[1][kc2], oacc[1][jd], 0, 0, 0);
      }
    }
  }

  // finalize: O = O^T / l (via v_rcp), 4B packed fp8 stores
  #pragma unroll
  for (int i = 0; i < 2; i++) {
    float inv = fast_rcp(l_run[i]);
    int n = q0 + wave * 32 + i * 16 + l16;
    #pragma unroll
    for (int jd = 0; jd < 4; jd++) {
      int p = to_fp8x4(oacc[i][jd][0] * inv, oacc[i][jd][1] * inv,
                       oacc[i][jd][2] * inv, oacc[i][jd][3] * inv);
      *(int*)(o + (size_t)(b * N_ + n) * C_ + h * HD_ + jd * 16 + quad * 4) = p;
    }
  }
}

// ---------------- host: workspace layout + launch ----------------
#define WQKVT_OFF  0u
#define WPROJT_OFF 1769472u
#define WFC1T_OFF  2359296u
#define WFC2T_OFF  4718592u
#define Y_OFF      7077888u
#define QKV_OFF    19660800u    // bf16 qkv (75.5 MB); aliased by fp8 hbuf (50.3 MB) after attn
#define VT_OFF     95158272u
#define O_OFF      120324096u
#define X1_OFF     132907008u
#define WS_NEEDED  183238656u

extern "C" void kernel_launch(void* const* d_in, const int* in_sizes, int n_in,
                              void* d_out, int out_size, void* d_ws, size_t ws_size,
                              hipStream_t stream) {
  if (ws_size < (size_t)WS_NEEDED) return;

  const float* x      = (const float*)d_in[0];
  const float* w_qkv  = (const float*)d_in[1];
  const float* w_proj = (const float*)d_in[2];
  const float* b_proj = (const float*)d_in[3];
  const float* ln1_g  = (const float*)d_in[4];
  const float* ln1_b  = (const float*)d_in[5];
  const float* ln2_g  = (const float*)d_in[6];
  const float* ln2_b  = (const float*)d_in[7];
  const float* ls1_g  = (const float*)d_in[8];
  const float* ls2_g  = (const float*)d_in[9];
  const float* w_fc1  = (const float*)d_in[10];
  const float* b_fc1  = (const float*)d_in[11];
  const float* w_fc2  = (const float*)d_in[12];
  const float* b_fc2  = (const float*)d_in[13];

  char* ws = (char*)d_ws;
  u8*    wqkvT  = (u8*)(ws + WQKVT_OFF);
  u8*    wprojT = (u8*)(ws + WPROJT_OFF);
  u8*    wfc1T  = (u8*)(ws + WFC1T_OFF);
  u8*    wfc2T  = (u8*)(ws + WFC2T_OFF);
  u8*    y      = (u8*)(ws + Y_OFF);
  bf16*  qkv    = (bf16*)(ws + QKV_OFF);
  u8*    hbuf   = (u8*)(ws + QKV_OFF);   // alias: qkv dead after attention
  f16*   vt     = (f16*)(ws + VT_OFF);
  u8*    o      = (u8*)(ws + O_OFF);
  float* x1     = (float*)(ws + X1_OFF);
  float* out    = (float*)d_out;

  dim3 tb(32, 8);
  transpose_cast<<<dim3(QKVN / 32, C_ / 32), tb, 0, stream>>>(w_qkv,  wqkvT,  C_,   QKVN);
  transpose_cast<<<dim3(C_   / 32, C_ / 32), tb, 0, stream>>>(w_proj, wprojT, C_,   C_);
  transpose_cast<<<dim3(MLP_ / 32, C_ / 32), tb, 0, stream>>>(w_fc1,  wfc1T,  C_,   MLP_);
  transpose_cast<<<dim3(C_ / 32, MLP_ / 32), tb, 0, stream>>>(w_fc2,  wfc2T,  MLP_, C_);

  ln_cast_kernel<<<M_, 256, 0, stream>>>(x, ln1_g, ln1_b, y);

  gemm_bt<0><<<(QKVN / 128) * 128, 256, 0, stream>>>(
      y, wqkvT, qkv, nullptr, nullptr, nullptr, M_, QKVN, C_, QKVN / 128);

  transpose_v<<<dim3(N_ / 32, HD_ / 32, B_ * H_), tb, 0, stream>>>(qkv, vt);

  attn_kernel<<<(N_ / 128) * B_ * H_, 256, 0, stream>>>(qkv, vt, o);

  gemm_bt<1><<<(C_ / 128) * 128, 256, 0, stream>>>(
      o, wprojT, x1, b_proj, ls1_g, x, M_, C_, C_, C_ / 128);

  ln_cast_kernel<<<M_, 256, 0, stream>>>(x1, ln2_g, ln2_b, y);

  gemm_bt<2><<<(MLP_ / 128) * 128, 256, 0, stream>>>(
      y, wfc1T, hbuf, b_fc1, nullptr, nullptr, M_, MLP_, C_, MLP_ / 128);

  gemm_bt<3><<<(C_ / 128) * 128, 256, 0, stream>>>(
      hbuf, wfc2T, out, b_fc2, ls2_g, x1, M_, C_, MLP_, C_ / 128);
}

// Round 9
// 499.644 us; speedup vs baseline: 1.6242x; 1.0015x over previous
//
#include <hip/hip_runtime.h>
#include <cstdint>
#include <cstddef>

// ---------------- types ----------------
typedef __bf16 bf16;
typedef __bf16 bf16x4 __attribute__((ext_vector_type(4)));
typedef __bf16 bf16x8 __attribute__((ext_vector_type(8)));
typedef _Float16 f16;
typedef _Float16 f16x4 __attribute__((ext_vector_type(4)));
typedef _Float16 f16x8 __attribute__((ext_vector_type(8)));
typedef float  f32x4  __attribute__((ext_vector_type(4)));
typedef unsigned char u8;

#define B_   16
#define N_   1024
#define C_   768
#define H_   12
#define HD_  64
#define M_   (B_*N_)      // 16384 rows
#define MLP_ 3072
#define QKVN 2304         // 3*C
#define WSCALE 64.0f      // weights cast to fp8 at x64 (0.02-scale weights are subnormal in e4m3)
#define WINV  (1.0f/64.0f)

__device__ __forceinline__ void gll16(const void* g, void* l) {
  __builtin_amdgcn_global_load_lds((const __attribute__((address_space(1))) void*)g,
                                   (__attribute__((address_space(3))) void*)l,
                                   16, 0, 0);
}

// native v_exp_f32 / v_rcp_f32 — libm forms lower to slow OCML sequences
__device__ __forceinline__ float fast_exp2(float x) { return __builtin_amdgcn_exp2f(x); }
__device__ __forceinline__ float fast_rcp(float x)  { return __builtin_amdgcn_rcpf(x); }

// fp8 e4m3 (OCP on gfx950) converts via HW packed cvt
__device__ __forceinline__ u8 to_fp8(float a) {
  return (u8)(__builtin_amdgcn_cvt_pk_fp8_f32(a, a, 0, false) & 0xff);
}
__device__ __forceinline__ int to_fp8x4(float v0, float v1, float v2, float v3) {
  int p = __builtin_amdgcn_cvt_pk_fp8_f32(v0, v1, 0, false);
  p = __builtin_amdgcn_cvt_pk_fp8_f32(v2, v3, p, true);
  return p;  // bytes [v0,v1,v2,v3]
}

// ---------------- fused prep: 4 weight transposes + LN1, one launch ----------------
// transpose tiles: qkv 72x24=1728 | proj 24x24=576 | fc1 96x24=2304 | fc2 24x96=2304
#define T_QKV  1728
#define T_PROJ 2304   // cumulative
#define T_FC1  4608
#define T_FC2  6912
#define T_ALL  6912

__device__ __forceinline__ void tc_tile(const float* __restrict__ w, u8* __restrict__ wt,
                                        int K, int N, int t, int tid) {
  __shared__ float tile[32][33];
  int tiles_n = N >> 5;
  int n0 = (t % tiles_n) * 32, k0 = (t / tiles_n) * 32;
  int tx = tid & 31, ty = tid >> 5;   // (32,8)
  #pragma unroll
  for (int i = 0; i < 32; i += 8)
    tile[ty + i][tx] = w[(size_t)(k0 + ty + i) * N + n0 + tx];
  __syncthreads();
  #pragma unroll
  for (int i = 0; i < 32; i += 8)
    wt[(size_t)(n0 + ty + i) * K + k0 + tx] = to_fp8(tile[tx][ty + i] * WSCALE);
}

__global__ __launch_bounds__(256)
void prep_kernel(const float* __restrict__ x,
                 const float* __restrict__ w_qkv, const float* __restrict__ w_proj,
                 const float* __restrict__ w_fc1, const float* __restrict__ w_fc2,
                 const float* __restrict__ g, const float* __restrict__ bta,
                 u8* __restrict__ wqkvT, u8* __restrict__ wprojT,
                 u8* __restrict__ wfc1T, u8* __restrict__ wfc2T,
                 u8* __restrict__ y) {
  int bid = blockIdx.x, tid = threadIdx.x;
  if (bid < T_ALL) {
    if (bid < T_QKV)       tc_tile(w_qkv,  wqkvT,  C_,   QKVN, bid,          tid);
    else if (bid < T_PROJ) tc_tile(w_proj, wprojT, C_,   C_,   bid - T_QKV,  tid);
    else if (bid < T_FC1)  tc_tile(w_fc1,  wfc1T,  C_,   MLP_, bid - T_PROJ, tid);
    else                   tc_tile(w_fc2,  wfc2T,  MLP_, C_,   bid - T_FC1,  tid);
    return;
  }
  // LayerNorm row
  int row = bid - T_ALL;
  const float* xr = x + (size_t)row * C_;
  float v0 = xr[tid], v1 = xr[tid + 256], v2 = xr[tid + 512];
  float s  = v0 + v1 + v2;
  float sq = v0 * v0 + v1 * v1 + v2 * v2;
  #pragma unroll
  for (int off = 32; off > 0; off >>= 1) {
    s  += __shfl_xor(s,  off);
    sq += __shfl_xor(sq, off);
  }
  __shared__ float red[8];
  int wave = tid >> 6, lane = tid & 63;
  if (lane == 0) { red[wave] = s; red[4 + wave] = sq; }
  __syncthreads();
  s  = red[0] + red[1] + red[2] + red[3];
  sq = red[4] + red[5] + red[6] + red[7];
  float mean = s * (1.0f / C_);
  float var  = sq * (1.0f / C_) - mean * mean;
  float rstd = rsqrtf(var + 1e-5f);
  u8* yr = y + (size_t)row * C_;
  yr[tid]       = to_fp8((v0 - mean) * rstd * g[tid]       + bta[tid]);
  yr[tid + 256] = to_fp8((v1 - mean) * rstd * g[tid + 256] + bta[tid + 256]);
  yr[tid + 512] = to_fp8((v2 - mean) * rstd * g[tid + 512] + bta[tid + 512]);
}

// ---------------- LayerNorm (768) + cast to fp8 (LN2) ----------------
__global__ __launch_bounds__(256)
void ln_cast_kernel(const float* __restrict__ x, const float* __restrict__ g,
                    const float* __restrict__ bta, u8* __restrict__ y) {
  int row = blockIdx.x;
  int tid = threadIdx.x;
  const float* xr = x + (size_t)row * C_;
  float v0 = xr[tid], v1 = xr[tid + 256], v2 = xr[tid + 512];
  float s  = v0 + v1 + v2;
  float sq = v0 * v0 + v1 * v1 + v2 * v2;
  #pragma unroll
  for (int off = 32; off > 0; off >>= 1) {
    s  += __shfl_xor(s,  off);
    sq += __shfl_xor(sq, off);
  }
  __shared__ float red[8];
  int wave = tid >> 6, lane = tid & 63;
  if (lane == 0) { red[wave] = s; red[4 + wave] = sq; }
  __syncthreads();
  s  = red[0] + red[1] + red[2] + red[3];
  sq = red[4] + red[5] + red[6] + red[7];
  float mean = s * (1.0f / C_);
  float var  = sq * (1.0f / C_) - mean * mean;
  float rstd = rsqrtf(var + 1e-5f);
  u8* yr = y + (size_t)row * C_;
  yr[tid]       = to_fp8((v0 - mean) * rstd * g[tid]       + bta[tid]);
  yr[tid + 256] = to_fp8((v1 - mean) * rstd * g[tid + 256] + bta[tid + 256]);
  yr[tid + 512] = to_fp8((v2 - mean) * rstd * g[tid + 512] + bta[tid + 512]);
}

// ---------------- fp8 GEMM: C[M,N] = A[M,K] @ Bt[N,K]^T, fp32 acc, result x(1/64) ----------
// XCD remap (R4) + LDS dbuf single-barrier (R6) + lean epilogue (R7).
// R8: K-loop SKEW — block (mi,ni) starts its circular K walk at skew = ni*iters/nb.
// The nb blocks sharing an m-tile warm disjoint K regions concurrently: cold A
// misses are split nb ways instead of one leader eating all of them (fp32 acc is
// order-invariant). Equalizes block durations -> kills the occupancy tail.
template <int EPI>
__global__ __launch_bounds__(256)
void gemm_bt(const u8* __restrict__ A, const u8* __restrict__ Bt,
             void* __restrict__ outp, const float* __restrict__ bias,
             const float* __restrict__ ls, const float* __restrict__ resid,
             int M, int N, int K, int nb) {
  constexpr int BM = 128, BN = 128, BK = 64;
  __shared__ __align__(16) u8 As[2][BM * BK];  // 2 x 8 KB
  __shared__ __align__(16) u8 Bs[2][BM * BK];  // 2 x 8 KB
  int tid  = threadIdx.x;
  int lane = tid & 63, wave = tid >> 6;
  int quad = lane >> 4, l16 = lane & 15;
  int bid = blockIdx.x;
  int xcd = bid & 7, seq = bid >> 3;
  int mi = xcd + 8 * (seq / nb), ni = seq % nb;
  int m0 = mi * BM, n0 = ni * BN;
  int wm = (wave >> 1) * 64, wn = (wave & 1) * 64;

  int iters = K >> 6;                 // K / BK
  int skew  = (ni * iters) / nb;      // < iters

  // staging source pointers, granule-swizzled at the global side
  const u8* ag[2]; const u8* bg[2];
  #pragma unroll
  for (int s = 0; s < 2; s++) {
    int u = tid + s * 256;
    int r = u >> 2, g = (u & 3) ^ ((r >> 1) & 3);
    ag[s] = A  + (size_t)(m0 + r) * K + g * 16;
    bg[s] = Bt + (size_t)(n0 + r) * K + g * 16;
  }
  int swz = (l16 >> 1) & 3;

  const f32x4 fz = {0.f, 0.f, 0.f, 0.f};
  f32x4 acc[4][4];
  #pragma unroll
  for (int i = 0; i < 4; i++)
    #pragma unroll
    for (int j = 0; j < 4; j++) acc[i][j] = fz;

  // prologue: stage tile 'skew' into buffer 0
  int kidx = skew;
  {
    int k0 = kidx * BK;
    gll16(ag[0] + k0, &As[0][0] + tid * 16);
    gll16(ag[1] + k0, &As[0][0] + 4096 + tid * 16);
    gll16(bg[0] + k0, &Bs[0][0] + tid * 16);
    gll16(bg[1] + k0, &Bs[0][0] + 4096 + tid * 16);
  }

  int buf = 0;
  for (int it = 0; it < iters; it++) {
    __syncthreads();   // drains vmcnt: tile kidx ready; other buf free
    int knext = kidx + 1; if (knext == iters) knext = 0;
    if (it + 1 < iters) { // prefetch next tile into the other buffer
      int kn = knext * BK;
      gll16(ag[0] + kn, &As[buf ^ 1][0] + tid * 16);
      gll16(ag[1] + kn, &As[buf ^ 1][0] + 4096 + tid * 16);
      gll16(bg[0] + kn, &Bs[buf ^ 1][0] + tid * 16);
      gll16(bg[1] + kn, &Bs[buf ^ 1][0] + 4096 + tid * 16);
    }
    #pragma unroll
    for (int kk = 0; kk < 2; kk++) {
      int go = (((kk << 1) | (quad >> 1)) ^ swz) * 16 + (quad & 1) * 8;
      long af[4], bfr[4];
      #pragma unroll
      for (int i = 0; i < 4; i++)
        af[i] = *(const long*)(&As[buf][0] + (wm + i * 16 + l16) * 64 + go);
      #pragma unroll
      for (int j = 0; j < 4; j++)
        bfr[j] = *(const long*)(&Bs[buf][0] + (wn + j * 16 + l16) * 64 + go);
      #pragma unroll
      for (int i = 0; i < 4; i++)
        #pragma unroll
        for (int j = 0; j < 4; j++)
          acc[i][j] = __builtin_amdgcn_mfma_f32_16x16x32_fp8_fp8(af[i], bfr[j],
                                                                 acc[i][j], 0, 0, 0);
    }
    kidx = knext;
    buf ^= 1;
  }

  // epilogue: D[row][col], row = quad*4 + r, col = l16 (per 16x16 frag)
  #pragma unroll
  for (int i = 0; i < 4; i++) {
    int rowb = m0 + wm + i * 16 + quad * 4;
    #pragma unroll
    for (int j = 0; j < 4; j++) {
      int col = n0 + wn + j * 16 + l16;
      float bias_c = (EPI == 0) ? 0.f : bias[col];
      float ls_c   = (EPI == 1 || EPI == 3) ? ls[col] : 0.f;
      float gz_v = -2.45546696f * WINV;
      float gz_b = -2.45546696f * bias_c;
      #pragma unroll
      for (int r = 0; r < 4; r++) {
        float v = acc[i][j][r];
        size_t idx = (size_t)(rowb + r) * N + col;
        if constexpr (EPI == 0) {
          ((bf16*)outp)[idx] = (bf16)(v * WINV);
        } else if constexpr (EPI == 1) {
          float t = fmaf(v, WINV, bias_c);
          ((float*)outp)[idx] = fmaf(t, ls_c, resid[idx]);
        } else if constexpr (EPI == 2) {
          float t  = fmaf(v, WINV, bias_c);
          float zn = fmaf(v, gz_v, gz_b);
          float gv = t * fast_rcp(1.0f + fast_exp2(zn));   // t * sigmoid(1.702 t)
          ((u8*)outp)[idx] = to_fp8(gv);
        } else {
          float t = fmaf(v, WINV, bias_c);
          ((float*)outp)[idx] = fmaf(t, ls_c, resid[idx]);
        }
      }
    }
  }
}

// ---------------- V transpose: qkv[.,1536+h*64+d] bf16 -> vt[bh][d][n] f16 ----------------
__global__ void transpose_v(const bf16* __restrict__ qkv, f16* __restrict__ vt) {
  __shared__ bf16 tile[32][33];
  int bh = blockIdx.z;
  int b = bh / H_, h = bh % H_;
  int n0 = blockIdx.x * 32, d0 = blockIdx.y * 32;
  int tx = threadIdx.x, ty = threadIdx.y;   // block (32,8)
  const bf16* src = qkv + (size_t)(b * N_) * QKVN + 2 * C_ + h * HD_;
  #pragma unroll
  for (int i = 0; i < 32; i += 8)
    tile[ty + i][tx] = src[(size_t)(n0 + ty + i) * QKVN + d0 + tx];
  __syncthreads();
  f16* dst = vt + (size_t)bh * HD_ * N_;
  #pragma unroll
  for (int i = 0; i < 32; i += 8)
    dst[(size_t)(d0 + ty + i) * N_ + n0 + tx] = (f16)(float)tile[tx][ty + i];
}

// ---------------- flash attention, S^T formulation ----------------
// 1-D grid 1536, XCD remap: bh = (bid&7) + 8*(seq>>3), q-tile = seq&7
// Register prefetch of next K/V tile; R8: kv-loop skewed by q-tile (online
// softmax is order-invariant) so the 8 q-blocks of one bh warm disjoint KV tiles.
__global__ __launch_bounds__(256)
void attn_kernel(const bf16* __restrict__ qkv, const f16* __restrict__ vt,
                 u8* __restrict__ o) {
  constexpr int KSTR = 72;    // K tile stride (64 + 8 pad), bf16
  constexpr int VSTR = 136;   // V^T tile stride (128 + 8 pad), f16
  __shared__ __align__(16) bf16 Ks[128 * KSTR];   // 18432 B
  __shared__ __align__(16) f16  Vs[HD_ * VSTR];   // 17408 B

  int tid = threadIdx.x, lane = tid & 63, wave = tid >> 6;
  int quad = lane >> 4, l16 = lane & 15;
  int bid = blockIdx.x;
  int xcd = bid & 7, seq = bid >> 3;
  int bh = xcd + 8 * (seq >> 3);
  int b = bh / H_, h = bh % H_;
  int qt = seq & 7;
  int q0 = qt * 128;
  const float CEXP = 0.125f * 1.44269504f;   // scale * log2(e)

  bf16x8 qf[2][2];
  #pragma unroll
  for (int i = 0; i < 2; i++)
    #pragma unroll
    for (int kk = 0; kk < 2; kk++)
      qf[i][kk] = *(const bf16x8*)(qkv + (size_t)(b * N_ + q0 + wave * 32 + i * 16 + l16) * QKVN
                                   + h * HD_ + kk * 32 + quad * 8);

  const f32x4 fz = {0.f, 0.f, 0.f, 0.f};
  f32x4 oacc[2][4];            // O^T[d = quad*4+r][q = l16]
  float m_run[2], l_run[2];
  #pragma unroll
  for (int i = 0; i < 2; i++) {
    #pragma unroll
    for (int jd = 0; jd < 4; jd++) oacc[i][jd] = fz;
    m_run[i] = -1e30f; l_run[i] = 0.f;
  }

  const bf16* kbase = qkv + (size_t)(b * N_) * QKVN + C_ + h * HD_;
  const f16*  vbase = vt + (size_t)bh * HD_ * N_;

  // per-thread staging coords
  int kr[4], kc[4], vr[4], vc[4];
  #pragma unroll
  for (int u = 0; u < 4; u++) {
    int L = tid + u * 256;
    kr[u] = L >> 3;  kc[u] = (L & 7) * 8;
    vr[u] = L >> 4;  vc[u] = (L & 15) * 8;
  }

  // prefetch first (skewed) tile into registers
  bf16x8 kreg[4]; f16x8 vreg[4];
  {
    int kv = qt * 128;   // skew start
    #pragma unroll
    for (int u = 0; u < 4; u++) {
      kreg[u] = *(const bf16x8*)(kbase + (size_t)(kv + kr[u]) * QKVN + kc[u]);
      vreg[u] = *(const f16x8*)(vbase + (size_t)vr[u] * N_ + kv + vc[u]);
    }
  }

  for (int t = 0; t < 8; t++) {
    __syncthreads();   // prior compute done reading LDS
    #pragma unroll
    for (int u = 0; u < 4; u++) {
      *(bf16x8*)(Ks + kr[u] * KSTR + kc[u]) = kreg[u];
      *(f16x8*)(Vs + vr[u] * VSTR + vc[u])  = vreg[u];
    }
    __syncthreads();

    // issue next (skewed) tile's loads; they complete during compute below
    if (t + 1 < 8) {
      int kv = ((t + 1 + qt) & 7) * 128;
      #pragma unroll
      for (int u = 0; u < 4; u++) {
        kreg[u] = *(const bf16x8*)(kbase + (size_t)(kv + kr[u]) * QKVN + kc[u]);
        vreg[u] = *(const f16x8*)(vbase + (size_t)vr[u] * N_ + kv + vc[u]);
      }
    }

    // S^T = K @ Q^T
    f32x4 sv[2][8];
    #pragma unroll
    for (int i = 0; i < 2; i++)
      #pragma unroll
      for (int kf = 0; kf < 8; kf++) sv[i][kf] = fz;
    #pragma unroll
    for (int kk = 0; kk < 2; kk++) {
      #pragma unroll
      for (int kf = 0; kf < 8; kf++) {
        bf16x8 kb = *(const bf16x8*)(Ks + (kf * 16 + l16) * KSTR + kk * 32 + quad * 8);
        sv[0][kf] = __builtin_amdgcn_mfma_f32_16x16x32_bf16(kb, qf[0][kk], sv[0][kf], 0, 0, 0);
        sv[1][kf] = __builtin_amdgcn_mfma_f32_16x16x32_bf16(kb, qf[1][kk], sv[1][kf], 0, 0, 0);
      }
    }

    // online softmax: keys in regs, queries on l16
    f16x4 pb[2][8];
    #pragma unroll
    for (int i = 0; i < 2; i++) {
      float mx = sv[i][0][0];
      #pragma unroll
      for (int kf = 0; kf < 8; kf++)
        #pragma unroll
        for (int r = 0; r < 4; r++) mx = fmaxf(mx, sv[i][kf][r]);
      mx = fmaxf(mx, __shfl_xor(mx, 16));
      mx = fmaxf(mx, __shfl_xor(mx, 32));
      float mold = m_run[i];
      float mnew = fmaxf(mold, mx);
      float mb   = mnew * CEXP;
      float al   = fast_exp2(mold * CEXP - mb);
      float rs = 0.f;
      #pragma unroll
      for (int kf = 0; kf < 8; kf++) {
        #pragma unroll
        for (int r = 0; r < 4; r++) {
          float p = fast_exp2(sv[i][kf][r] * CEXP - mb);
          pb[i][kf][r] = (f16)p;
          rs += p;
        }
      }
      rs += __shfl_xor(rs, 16);
      rs += __shfl_xor(rs, 32);
      m_run[i] = mnew;
      l_run[i] = l_run[i] * al + rs;
      #pragma unroll
      for (int jd = 0; jd < 4; jd++) oacc[i][jd] *= al;
    }

    // O^T += V^T @ P^T
    #pragma unroll
    for (int kc2 = 0; kc2 < 8; kc2++) {
      #pragma unroll
      for (int jd = 0; jd < 4; jd++) {
        f16x4 va = *(const f16x4*)(Vs + (jd * 16 + l16) * VSTR + kc2 * 16 + quad * 4);
        oacc[0][jd] = __builtin_amdgcn_mfma_f32_16x16x16f16(va, pb[0][kc2], oacc[0][jd], 0, 0, 0);
        oacc[1][jd] = __builtin_amdgcn_mfma_f32_16x16x16f16(va, pb[1][kc2], oacc[1][jd], 0, 0, 0);
      }
    }
  }

  // finalize: O = O^T / l (via v_rcp), 4B packed fp8 stores
  #pragma unroll
  for (int i = 0; i < 2; i++) {
    float inv = fast_rcp(l_run[i]);
    int n = q0 + wave * 32 + i * 16 + l16;
    #pragma unroll
    for (int jd = 0; jd < 4; jd++) {
      int p = to_fp8x4(oacc[i][jd][0] * inv, oacc[i][jd][1] * inv,
                       oacc[i][jd][2] * inv, oacc[i][jd][3] * inv);
      *(int*)(o + (size_t)(b * N_ + n) * C_ + h * HD_ + jd * 16 + quad * 4) = p;
    }
  }
}

// ---------------- host: workspace layout + launch ----------------
#define WQKVT_OFF  0u
#define WPROJT_OFF 1769472u
#define WFC1T_OFF  2359296u
#define WFC2T_OFF  4718592u
#define Y_OFF      7077888u
#define QKV_OFF    19660800u    // bf16 qkv (75.5 MB); aliased by fp8 hbuf (50.3 MB) after attn
#define VT_OFF     95158272u
#define O_OFF      120324096u
#define X1_OFF     132907008u
#define WS_NEEDED  183238656u

extern "C" void kernel_launch(void* const* d_in, const int* in_sizes, int n_in,
                              void* d_out, int out_size, void* d_ws, size_t ws_size,
                              hipStream_t stream) {
  if (ws_size < (size_t)WS_NEEDED) return;

  const float* x      = (const float*)d_in[0];
  const float* w_qkv  = (const float*)d_in[1];
  const float* w_proj = (const float*)d_in[2];
  const float* b_proj = (const float*)d_in[3];
  const float* ln1_g  = (const float*)d_in[4];
  const float* ln1_b  = (const float*)d_in[5];
  const float* ln2_g  = (const float*)d_in[6];
  const float* ln2_b  = (const float*)d_in[7];
  const float* ls1_g  = (const float*)d_in[8];
  const float* ls2_g  = (const float*)d_in[9];
  const float* w_fc1  = (const float*)d_in[10];
  const float* b_fc1  = (const float*)d_in[11];
  const float* w_fc2  = (const float*)d_in[12];
  const float* b_fc2  = (const float*)d_in[13];

  char* ws = (char*)d_ws;
  u8*    wqkvT  = (u8*)(ws + WQKVT_OFF);
  u8*    wprojT = (u8*)(ws + WPROJT_OFF);
  u8*    wfc1T  = (u8*)(ws + WFC1T_OFF);
  u8*    wfc2T  = (u8*)(ws + WFC2T_OFF);
  u8*    y      = (u8*)(ws + Y_OFF);
  bf16*  qkv    = (bf16*)(ws + QKV_OFF);
  u8*    hbuf   = (u8*)(ws + QKV_OFF);   // alias: qkv dead after attention
  f16*   vt     = (f16*)(ws + VT_OFF);
  u8*    o      = (u8*)(ws + O_OFF);
  float* x1     = (float*)(ws + X1_OFF);
  float* out    = (float*)d_out;

  // fused: 4 weight transposes + LN1
  prep_kernel<<<T_ALL + M_, 256, 0, stream>>>(
      x, w_qkv, w_proj, w_fc1, w_fc2, ln1_g, ln1_b,
      wqkvT, wprojT, wfc1T, wfc2T, y);

  gemm_bt<0><<<(QKVN / 128) * 128, 256, 0, stream>>>(
      y, wqkvT, qkv, nullptr, nullptr, nullptr, M_, QKVN, C_, QKVN / 128);

  dim3 tb(32, 8);
  transpose_v<<<dim3(N_ / 32, HD_ / 32, B_ * H_), tb, 0, stream>>>(qkv, vt);

  attn_kernel<<<(N_ / 128) * B_ * H_, 256, 0, stream>>>(qkv, vt, o);

  gemm_bt<1><<<(C_ / 128) * 128, 256, 0, stream>>>(
      o, wprojT, x1, b_proj, ls1_g, x, M_, C_, C_, C_ / 128);

  ln_cast_kernel<<<M_, 256, 0, stream>>>(x1, ln2_g, ln2_b, y);

  gemm_bt<2><<<(MLP_ / 128) * 128, 256, 0, stream>>>(
      y, wfc1T, hbuf, b_fc1, nullptr, nullptr, M_, MLP_, C_, MLP_ / 128);

  gemm_bt<3><<<(C_ / 128) * 128, 256, 0, stream>>>(
      hbuf, wfc2T, out, b_fc2, ls2_g, x1, M_, C_, MLP_, C_ / 128);
}